// Round 3
// baseline (453.496 us; speedup 1.0000x reference)
//
#include <hip/hip_runtime.h>

#define CH 64

// ---------------------------------------------------------------------------
// Pass 1: per-node minmax norm + three 64x64 projections.
// One wave per node. Each lane owns output channel `lane`; the three W-columns
// live in 192 VGPRs (static-indexed unrolled arrays). The normalized x-row is
// staged in a per-wave LDS buffer and read back as float4 broadcasts.
// ---------------------------------------------------------------------------
__global__ __launch_bounds__(256) void proj_kernel(
    const float* __restrict__ nd,
    const float* __restrict__ W1, const float* __restrict__ b1,
    const float* __restrict__ W2, const float* __restrict__ b2,
    const float* __restrict__ Wr, const float* __restrict__ br,
    float* __restrict__ lbuf, float* __restrict__ rbuf,
    float* __restrict__ hres, int N)
{
    __shared__ __align__(16) float xs[4][CH];
    const int lane = threadIdx.x & 63;
    const int wid  = threadIdx.x >> 6;

    float w1[CH], w2[CH], wr[CH];
#pragma unroll
    for (int i = 0; i < CH; ++i) {
        w1[i] = W1[i * CH + lane];
        w2[i] = W2[i * CH + lane];
        wr[i] = Wr[i * CH + lane];
    }
    const float bb1 = b1[lane], bb2 = b2[lane], bbr = br[lane];

    const int nwave = gridDim.x * 4;
    for (int node = blockIdx.x * 4 + wid; node < N; node += nwave) {
        const size_t row = (size_t)node * CH;
        float v = nd[row + lane];
        float mn = v, mx = v;
#pragma unroll
        for (int off = 32; off; off >>= 1) {
            mn = fminf(mn, __shfl_xor(mn, off));
            mx = fmaxf(mx, __shfl_xor(mx, off));
        }
        float x = (v - mn) / (mx - mn + 1e-5f);
        xs[wid][lane] = x;
        float a1 = bb1, a2 = bb2, a3 = bbr;
        const float4* x4 = reinterpret_cast<const float4*>(&xs[wid][0]);
#pragma unroll
        for (int k = 0; k < CH / 4; ++k) {
            float4 xv = x4[k];
            a1 = fmaf(xv.x, w1[4*k+0], a1);
            a1 = fmaf(xv.y, w1[4*k+1], a1);
            a1 = fmaf(xv.z, w1[4*k+2], a1);
            a1 = fmaf(xv.w, w1[4*k+3], a1);
            a2 = fmaf(xv.x, w2[4*k+0], a2);
            a2 = fmaf(xv.y, w2[4*k+1], a2);
            a2 = fmaf(xv.z, w2[4*k+2], a2);
            a2 = fmaf(xv.w, w2[4*k+3], a2);
            a3 = fmaf(xv.x, wr[4*k+0], a3);
            a3 = fmaf(xv.y, wr[4*k+1], a3);
            a3 = fmaf(xv.z, wr[4*k+2], a3);
            a3 = fmaf(xv.w, wr[4*k+3], a3);
        }
        lbuf[row + lane] = a1;
        rbuf[row + lane] = a2;
        hres[row + lane] = a3;   // residual projection straight into d_out
    }
}

// ---------------------------------------------------------------------------
// CSR build: histogram -> single-block scan -> scatter.
// Edge list = original E edges + N self loops (edge id >= E is self loop).
// ---------------------------------------------------------------------------
__global__ void count_kernel(const int* __restrict__ dst, int* __restrict__ deg,
                             int E, int N)
{
    int total = E + N;
    for (int i = blockIdx.x * blockDim.x + threadIdx.x; i < total;
         i += gridDim.x * blockDim.x) {
        int d = (i < E) ? dst[i] : (i - E);
        atomicAdd(&deg[d], 1);
    }
}

__global__ __launch_bounds__(1024) void scan_kernel(
    const int* __restrict__ deg, int* __restrict__ rowptr,
    int* __restrict__ cursor, int N)
{
    __shared__ int wsum[16];
    __shared__ int carry;
    const int tid = threadIdx.x, lane = tid & 63, wid = tid >> 6;
    if (tid == 0) carry = 0;
    __syncthreads();
    for (int base = 0; base < N; base += 1024) {
        int i = base + tid;
        int v = (i < N) ? deg[i] : 0;
        int s = v;
#pragma unroll
        for (int off = 1; off < 64; off <<= 1) {
            int t = __shfl_up(s, off);
            if (lane >= off) s += t;
        }
        if (lane == 63) wsum[wid] = s;
        __syncthreads();
        if (wid == 0) {
            int w = (lane < 16) ? wsum[lane] : 0;
            int ws = w;
#pragma unroll
            for (int off = 1; off < 16; off <<= 1) {
                int t = __shfl_up(ws, off);
                if (lane >= off) ws += t;
            }
            if (lane < 16) wsum[lane] = ws - w;   // exclusive per-wave offset
        }
        __syncthreads();
        int excl = carry + wsum[wid] + (s - v);
        if (i < N) { rowptr[i] = excl; cursor[i] = excl; }
        __syncthreads();
        if (tid == 1023) carry += wsum[15] + s;   // chunk total
        __syncthreads();
    }
    if (tid == 0) rowptr[N] = carry;
}

__global__ void scatter_kernel(const int* __restrict__ src,
                               const int* __restrict__ dst,
                               int* __restrict__ cursor, int* __restrict__ col,
                               int E, int N)
{
    int total = E + N;
    for (int i = blockIdx.x * blockDim.x + threadIdx.x; i < total;
         i += gridDim.x * blockDim.x) {
        int s, d;
        if (i < E) { s = src[i]; d = dst[i]; }
        else       { s = i - E;  d = i - E; }
        int slot = atomicAdd(&cursor[d], 1);
        col[slot] = s;
    }
}

// ---------------------------------------------------------------------------
// Pass A: per dst node (one wave, lane = channel):
//   denL = sum_e exp(sig(l[s]+l[d]))         (softmax denominator, no max
//   acc  = sum_e r[s]*exp(sig(l[s]+l[d]))     needed: sigmoid in (0,1))
//   denR = sum_e exp(sig(r[s]+r[d]))
//   ft_r = acc / denL   (softmax denominator factored out of segment_sum)
// ---------------------------------------------------------------------------
__global__ __launch_bounds__(256) void passA_kernel(
    const float* __restrict__ lbuf, const float* __restrict__ rbuf,
    const int* __restrict__ rowptr, const int* __restrict__ col,
    float* __restrict__ ftr, float* __restrict__ denR, int N)
{
    const int node = blockIdx.x * 4 + (threadIdx.x >> 6);
    const int lane = threadIdx.x & 63;
    if (node >= N) return;
    const size_t row = (size_t)node * CH;
    const float l_d = lbuf[row + lane];
    const float r_d = rbuf[row + lane];
    const int beg = rowptr[node], end = rowptr[node + 1];
    float denL = 0.f, dR = 0.f, acc = 0.f;
    for (int e = beg; e < end; ++e) {
        int s = __builtin_amdgcn_readfirstlane(col[e]);
        const size_t srow = (size_t)s * CH;
        float lv = lbuf[srow + lane];
        float rv = rbuf[srow + lane];
        float sl = 1.f / (1.f + __expf(-(lv + l_d)));
        float exl = __expf(sl);
        denL += exl;
        acc  = fmaf(rv, exl, acc);
        float sr = 1.f / (1.f + __expf(-(rv + r_d)));
        dR += __expf(sr);
    }
    ftr[row + lane]  = acc / denL;
    denR[row + lane] = dR;
}

// ---------------------------------------------------------------------------
// Pass B: per dst node: ft_l = (sum_e ftr[s]*exp(sig(r[s]+r[d]))) / denR
//         out = m0 * ft_l + hres   (hres already in d_out from pass 1)
// ---------------------------------------------------------------------------
__global__ __launch_bounds__(256) void passB_kernel(
    const float* __restrict__ rbuf, const float* __restrict__ ftr,
    const float* __restrict__ denR,
    const int* __restrict__ rowptr, const int* __restrict__ col,
    const float* __restrict__ m0, float* __restrict__ out, int N)
{
    const int node = blockIdx.x * 4 + (threadIdx.x >> 6);
    const int lane = threadIdx.x & 63;
    if (node >= N) return;
    const size_t row = (size_t)node * CH;
    const float r_d = rbuf[row + lane];
    const float dR  = denR[row + lane];
    const int beg = rowptr[node], end = rowptr[node + 1];
    float acc = 0.f;
    for (int e = beg; e < end; ++e) {
        int s = __builtin_amdgcn_readfirstlane(col[e]);
        const size_t srow = (size_t)s * CH;
        float rv = rbuf[srow + lane];
        float fv = ftr[srow + lane];
        float sr = 1.f / (1.f + __expf(-(rv + r_d)));
        acc = fmaf(fv, __expf(sr), acc);
    }
    out[row + lane] = fmaf(m0[lane], acc / dR, out[row + lane]);
}

// ---------------------------------------------------------------------------
extern "C" void kernel_launch(void* const* d_in, const int* in_sizes, int n_in,
                              void* d_out, int out_size, void* d_ws, size_t ws_size,
                              hipStream_t stream)
{
    const float* ndata = (const float*)d_in[0];
    const int*   src   = (const int*)d_in[1];
    const int*   dst   = (const int*)d_in[2];
    const float* W1    = (const float*)d_in[3];
    const float* b1    = (const float*)d_in[4];
    const float* W2    = (const float*)d_in[5];
    const float* b2    = (const float*)d_in[6];
    const float* Wr    = (const float*)d_in[7];
    const float* br    = (const float*)d_in[8];
    const float* m     = (const float*)d_in[9];   // [3,8,8]; m[0] flat = 64
    float* out = (float*)d_out;

    const int N = in_sizes[0] / CH;
    const int E = in_sizes[1];

    char* ws = (char*)d_ws;
    size_t off = 0;
    auto alloc = [&](size_t bytes) -> void* {
        void* p = ws + off;
        off = (off + bytes + 255) & ~(size_t)255;
        return p;
    };
    float* lbuf   = (float*)alloc((size_t)N * CH * 4);
    float* rbuf   = (float*)alloc((size_t)N * CH * 4);
    float* ftr    = (float*)alloc((size_t)N * CH * 4);
    float* denR   = (float*)alloc((size_t)N * CH * 4);
    int*   deg    = (int*)alloc((size_t)N * 4);
    int*   rowptr = (int*)alloc((size_t)(N + 1) * 4);
    int*   cursor = (int*)alloc((size_t)N * 4);
    int*   col    = (int*)alloc((size_t)(E + N) * 4);

    hipMemsetAsync(deg, 0, (size_t)N * 4, stream);
    count_kernel<<<1024, 256, 0, stream>>>(dst, deg, E, N);
    proj_kernel<<<512, 256, 0, stream>>>(ndata, W1, b1, W2, b2, Wr, br,
                                         lbuf, rbuf, out, N);
    scan_kernel<<<1, 1024, 0, stream>>>(deg, rowptr, cursor, N);
    scatter_kernel<<<1024, 256, 0, stream>>>(src, dst, cursor, col, E, N);
    int nb = (N + 3) / 4;
    passA_kernel<<<nb, 256, 0, stream>>>(lbuf, rbuf, rowptr, col, ftr, denR, N);
    passB_kernel<<<nb, 256, 0, stream>>>(rbuf, ftr, denR, rowptr, col, m, out, N);
}

// Round 4
// 327.268 us; speedup vs baseline: 1.3857x; 1.3857x over previous
//
#include <hip/hip_runtime.h>
#include <hip/hip_fp16.h>

#define CH 64

// ---------------------------------------------------------------------------
// proj: per-node minmax norm + three 64x64 GEMVs.
// Writes lr[node][ch] = half2(l, r)  (fp16, one dword per channel -> a single
// gathered dword in passA serves both values) and the residual into d_out.
// ---------------------------------------------------------------------------
__global__ __launch_bounds__(256) void proj_kernel(
    const float* __restrict__ nd,
    const float* __restrict__ W1, const float* __restrict__ b1,
    const float* __restrict__ W2, const float* __restrict__ b2,
    const float* __restrict__ Wr, const float* __restrict__ br,
    __half2* __restrict__ lr, float* __restrict__ hres, int N)
{
    __shared__ __align__(16) float xs[4][CH];
    const int lane = threadIdx.x & 63;
    const int wid  = threadIdx.x >> 6;

    float w1[CH], w2[CH], wr[CH];
#pragma unroll
    for (int i = 0; i < CH; ++i) {
        w1[i] = W1[i * CH + lane];
        w2[i] = W2[i * CH + lane];
        wr[i] = Wr[i * CH + lane];
    }
    const float bb1 = b1[lane], bb2 = b2[lane], bbr = br[lane];

    const int nwave = gridDim.x * 4;
    for (int node = blockIdx.x * 4 + wid; node < N; node += nwave) {
        const size_t row = (size_t)node * CH;
        float v = nd[row + lane];
        float mn = v, mx = v;
#pragma unroll
        for (int off = 32; off; off >>= 1) {
            mn = fminf(mn, __shfl_xor(mn, off));
            mx = fmaxf(mx, __shfl_xor(mx, off));
        }
        float x = (v - mn) / (mx - mn + 1e-5f);
        xs[wid][lane] = x;
        float a1 = bb1, a2 = bb2, a3 = bbr;
        const float4* x4 = reinterpret_cast<const float4*>(&xs[wid][0]);
#pragma unroll
        for (int k = 0; k < CH / 4; ++k) {
            float4 xv = x4[k];
            a1 = fmaf(xv.x, w1[4*k+0], a1);
            a1 = fmaf(xv.y, w1[4*k+1], a1);
            a1 = fmaf(xv.z, w1[4*k+2], a1);
            a1 = fmaf(xv.w, w1[4*k+3], a1);
            a2 = fmaf(xv.x, w2[4*k+0], a2);
            a2 = fmaf(xv.y, w2[4*k+1], a2);
            a2 = fmaf(xv.z, w2[4*k+2], a2);
            a2 = fmaf(xv.w, w2[4*k+3], a2);
            a3 = fmaf(xv.x, wr[4*k+0], a3);
            a3 = fmaf(xv.y, wr[4*k+1], a3);
            a3 = fmaf(xv.z, wr[4*k+2], a3);
            a3 = fmaf(xv.w, wr[4*k+3], a3);
        }
        lr[row + lane]   = __floats2half2_rn(a1, a2);
        hres[row + lane] = a3;   // residual straight into d_out
    }
}

// ---------------------------------------------------------------------------
// CSR build: histogram -> 3-kernel multi-block scan -> scatter.
// Edge id >= E is the self loop (i-E, i-E).
// ---------------------------------------------------------------------------
__global__ void count_kernel(const int* __restrict__ dst, int* __restrict__ deg,
                             int E, int N)
{
    int total = E + N;
    for (int i = blockIdx.x * blockDim.x + threadIdx.x; i < total;
         i += gridDim.x * blockDim.x) {
        int d = (i < E) ? dst[i] : (i - E);
        atomicAdd(&deg[d], 1);
    }
}

// per-256-element block sums
__global__ __launch_bounds__(256) void bsum_kernel(
    const int* __restrict__ deg, int* __restrict__ bsum, int N)
{
    __shared__ int ws[4];
    int i = blockIdx.x * 256 + threadIdx.x;
    int lane = threadIdx.x & 63, wid = threadIdx.x >> 6;
    int v = (i < N) ? deg[i] : 0;
#pragma unroll
    for (int off = 32; off; off >>= 1) v += __shfl_xor(v, off);
    if (lane == 0) ws[wid] = v;
    __syncthreads();
    if (threadIdx.x == 0) bsum[blockIdx.x] = ws[0] + ws[1] + ws[2] + ws[3];
}

// exclusive scan of block sums (single wave, chunks of 64 with carry)
__global__ __launch_bounds__(64) void bscan_kernel(int* __restrict__ bsum, int nb)
{
    int lane = threadIdx.x;
    int carry = 0;
    for (int base = 0; base < nb; base += 64) {
        int i = base + lane;
        int v = (i < nb) ? bsum[i] : 0;
        int s = v;
#pragma unroll
        for (int off = 1; off < 64; off <<= 1) {
            int t = __shfl_up(s, off);
            if (lane >= off) s += t;
        }
        if (i < nb) bsum[i] = carry + s - v;   // exclusive
        carry += __shfl(s, 63);
    }
}

// rowptr[i] = bsum[block] + intra-block exclusive scan; cursor = rowptr
__global__ __launch_bounds__(256) void apply_kernel(
    const int* __restrict__ deg, const int* __restrict__ bsum,
    int* __restrict__ rowptr, int* __restrict__ cursor, int N, int total)
{
    __shared__ int ws[4];
    int i = blockIdx.x * 256 + threadIdx.x;
    int lane = threadIdx.x & 63, wid = threadIdx.x >> 6;
    int v = (i < N) ? deg[i] : 0;
    int s = v;
#pragma unroll
    for (int off = 1; off < 64; off <<= 1) {
        int t = __shfl_up(s, off);
        if (lane >= off) s += t;
    }
    if (lane == 63) ws[wid] = s;
    __syncthreads();
    int woff = 0;
    for (int w = 0; w < wid; ++w) woff += ws[w];
    int excl = bsum[blockIdx.x] + woff + s - v;
    if (i < N) { rowptr[i] = excl; cursor[i] = excl; }
    if (blockIdx.x == 0 && threadIdx.x == 0) rowptr[N] = total;
}

__global__ void scatter_kernel(const int* __restrict__ src,
                               const int* __restrict__ dst,
                               int* __restrict__ cursor, int* __restrict__ col,
                               int E, int N)
{
    int total = E + N;
    for (int i = blockIdx.x * blockDim.x + threadIdx.x; i < total;
         i += gridDim.x * blockDim.x) {
        int s, d;
        if (i < E) { s = src[i]; d = dst[i]; }
        else       { s = i - E;  d = i - E; }
        int slot = atomicAdd(&cursor[d], 1);
        col[slot] = s;
    }
}

// ---------------------------------------------------------------------------
// Pass A: per dst node (one wave, lane = channel). Softmax max-pass dropped
// (sigmoid in (0,1)); denominator factored out of the segment sum.
// Edge indices pre-loaded 64-wide + v_readlane broadcast; edge loop unrolled
// x4 with all 4 half2 row-gathers issued before the exp chains (MLP=4).
// ---------------------------------------------------------------------------
__global__ __launch_bounds__(256) void passA_kernel(
    const __half2* __restrict__ lr,
    const int* __restrict__ rowptr, const int* __restrict__ col,
    __half2* __restrict__ rf, float* __restrict__ denR, int N)
{
    const int node = blockIdx.x * 4 + (threadIdx.x >> 6);
    const int lane = threadIdx.x & 63;
    if (node >= N) return;
    const size_t row = (size_t)node * CH;
    const float2 own = __half22float2(lr[row + lane]);
    const float l_d = own.x, r_d = own.y;
    const int beg = rowptr[node], end = rowptr[node + 1];

    float denL = 0.f, dR = 0.f, acc = 0.f;
    auto edge = [&](float2 f) {
        float sl = 1.f / (1.f + __expf(-(f.x + l_d)));
        float ex = __expf(sl);
        denL += ex;
        acc = fmaf(f.y, ex, acc);
        float sr = 1.f / (1.f + __expf(-(f.y + r_d)));
        dR += __expf(sr);
    };

    int e = beg;
    while (e < end) {
        int cnt = end - e; if (cnt > 64) cnt = 64;
        int idx = e + lane; if (idx >= end) idx = end - 1;
        const int myc = col[idx];
        int j = 0;
        for (; j + 4 <= cnt; j += 4) {
            int s0 = __builtin_amdgcn_readlane(myc, j);
            int s1 = __builtin_amdgcn_readlane(myc, j + 1);
            int s2 = __builtin_amdgcn_readlane(myc, j + 2);
            int s3 = __builtin_amdgcn_readlane(myc, j + 3);
            float2 f0 = __half22float2(lr[(size_t)s0 * CH + lane]);
            float2 f1 = __half22float2(lr[(size_t)s1 * CH + lane]);
            float2 f2 = __half22float2(lr[(size_t)s2 * CH + lane]);
            float2 f3 = __half22float2(lr[(size_t)s3 * CH + lane]);
            edge(f0); edge(f1); edge(f2); edge(f3);
        }
        for (; j < cnt; ++j) {
            int s0 = __builtin_amdgcn_readlane(myc, j);
            edge(__half22float2(lr[(size_t)s0 * CH + lane]));
        }
        e += cnt;
    }
    rf[row + lane]   = __floats2half2_rn(r_d, acc / denL);  // (r, ft_r)
    denR[row + lane] = dR;
}

// ---------------------------------------------------------------------------
// Pass B: ft_l = (sum_e ftr[s]*exp(sig(r[s]+r[d]))) / denR ; out += m0*ft_l
// One half2 gather per edge supplies (r_s, ftr_s).
// ---------------------------------------------------------------------------
__global__ __launch_bounds__(256) void passB_kernel(
    const __half2* __restrict__ rf, const float* __restrict__ denR,
    const int* __restrict__ rowptr, const int* __restrict__ col,
    const float* __restrict__ m0, float* __restrict__ out, int N)
{
    const int node = blockIdx.x * 4 + (threadIdx.x >> 6);
    const int lane = threadIdx.x & 63;
    if (node >= N) return;
    const size_t row = (size_t)node * CH;
    const float r_d = __half22float2(rf[row + lane]).x;
    const float dR  = denR[row + lane];
    const int beg = rowptr[node], end = rowptr[node + 1];

    float acc = 0.f;
    auto edge = [&](float2 f) {
        float sr = 1.f / (1.f + __expf(-(f.x + r_d)));
        acc = fmaf(f.y, __expf(sr), acc);
    };

    int e = beg;
    while (e < end) {
        int cnt = end - e; if (cnt > 64) cnt = 64;
        int idx = e + lane; if (idx >= end) idx = end - 1;
        const int myc = col[idx];
        int j = 0;
        for (; j + 4 <= cnt; j += 4) {
            int s0 = __builtin_amdgcn_readlane(myc, j);
            int s1 = __builtin_amdgcn_readlane(myc, j + 1);
            int s2 = __builtin_amdgcn_readlane(myc, j + 2);
            int s3 = __builtin_amdgcn_readlane(myc, j + 3);
            float2 f0 = __half22float2(rf[(size_t)s0 * CH + lane]);
            float2 f1 = __half22float2(rf[(size_t)s1 * CH + lane]);
            float2 f2 = __half22float2(rf[(size_t)s2 * CH + lane]);
            float2 f3 = __half22float2(rf[(size_t)s3 * CH + lane]);
            edge(f0); edge(f1); edge(f2); edge(f3);
        }
        for (; j < cnt; ++j) {
            int s0 = __builtin_amdgcn_readlane(myc, j);
            edge(__half22float2(rf[(size_t)s0 * CH + lane]));
        }
        e += cnt;
    }
    out[row + lane] = fmaf(m0[lane], acc / dR, out[row + lane]);
}

// ---------------------------------------------------------------------------
extern "C" void kernel_launch(void* const* d_in, const int* in_sizes, int n_in,
                              void* d_out, int out_size, void* d_ws, size_t ws_size,
                              hipStream_t stream)
{
    const float* ndata = (const float*)d_in[0];
    const int*   src   = (const int*)d_in[1];
    const int*   dst   = (const int*)d_in[2];
    const float* W1    = (const float*)d_in[3];
    const float* b1    = (const float*)d_in[4];
    const float* W2    = (const float*)d_in[5];
    const float* b2    = (const float*)d_in[6];
    const float* Wr    = (const float*)d_in[7];
    const float* br    = (const float*)d_in[8];
    const float* m     = (const float*)d_in[9];   // [3,8,8]; m[0] flat = 64
    float* out = (float*)d_out;

    const int N = in_sizes[0] / CH;
    const int E = in_sizes[1];
    const int nbk = (N + 255) / 256;   // scan blocks

    char* ws = (char*)d_ws;
    size_t off = 0;
    auto alloc = [&](size_t bytes) -> void* {
        void* p = ws + off;
        off = (off + bytes + 255) & ~(size_t)255;
        return p;
    };
    __half2* lr   = (__half2*)alloc((size_t)N * CH * 4);
    __half2* rf   = (__half2*)alloc((size_t)N * CH * 4);
    float* denR   = (float*)alloc((size_t)N * CH * 4);
    int*   deg    = (int*)alloc((size_t)N * 4);
    int*   bsum   = (int*)alloc((size_t)nbk * 4);
    int*   rowptr = (int*)alloc((size_t)(N + 1) * 4);
    int*   cursor = (int*)alloc((size_t)N * 4);
    int*   col    = (int*)alloc((size_t)(E + N) * 4);

    hipMemsetAsync(deg, 0, (size_t)N * 4, stream);
    count_kernel<<<1024, 256, 0, stream>>>(dst, deg, E, N);
    proj_kernel<<<512, 256, 0, stream>>>(ndata, W1, b1, W2, b2, Wr, br,
                                         lr, out, N);
    bsum_kernel<<<nbk, 256, 0, stream>>>(deg, bsum, N);
    bscan_kernel<<<1, 64, 0, stream>>>(bsum, nbk);
    apply_kernel<<<nbk, 256, 0, stream>>>(deg, bsum, rowptr, cursor, N, E + N);
    scatter_kernel<<<1024, 256, 0, stream>>>(src, dst, cursor, col, E, N);
    int nb = (N + 3) / 4;
    passA_kernel<<<nb, 256, 0, stream>>>(lr, rowptr, col, rf, denR, N);
    passB_kernel<<<nb, 256, 0, stream>>>(rf, denR, rowptr, col, m, out, N);
}

// Round 5
// 285.284 us; speedup vs baseline: 1.5896x; 1.1472x over previous
//
#include <hip/hip_runtime.h>
#include <hip/hip_fp16.h>

#define CH 64

// ---------------------------------------------------------------------------
// proj: per-node minmax norm + three 64x64 GEMVs -> lr[node][ch]=half2(l,r),
// residual into d_out. Tail: fused edge-degree count; the atomicAdd return
// value is the edge's rank within its dst segment (used by scatter, no atomic).
// ---------------------------------------------------------------------------
__global__ __launch_bounds__(256) void proj_kernel(
    const float* __restrict__ nd,
    const float* __restrict__ W1, const float* __restrict__ b1,
    const float* __restrict__ W2, const float* __restrict__ b2,
    const float* __restrict__ Wr, const float* __restrict__ br,
    __half2* __restrict__ lr, float* __restrict__ hres,
    const int* __restrict__ dst, int* __restrict__ deg,
    int* __restrict__ rank, int N, int E)
{
    __shared__ __align__(16) float xs[4][CH];
    const int lane = threadIdx.x & 63;
    const int wid  = threadIdx.x >> 6;

    float w1[CH], w2[CH], wr[CH];
#pragma unroll
    for (int i = 0; i < CH; ++i) {
        w1[i] = W1[i * CH + lane];
        w2[i] = W2[i * CH + lane];
        wr[i] = Wr[i * CH + lane];
    }
    const float bb1 = b1[lane], bb2 = b2[lane], bbr = br[lane];

    const int nwave = gridDim.x * 4;
    for (int node = blockIdx.x * 4 + wid; node < N; node += nwave) {
        const unsigned row = (unsigned)node * CH;
        float v = nd[row + lane];
        float mn = v, mx = v;
#pragma unroll
        for (int off = 32; off; off >>= 1) {
            mn = fminf(mn, __shfl_xor(mn, off));
            mx = fmaxf(mx, __shfl_xor(mx, off));
        }
        float x = (v - mn) / (mx - mn + 1e-5f);
        xs[wid][lane] = x;
        float a1 = bb1, a2 = bb2, a3 = bbr;
        const float4* x4 = reinterpret_cast<const float4*>(&xs[wid][0]);
#pragma unroll
        for (int k = 0; k < CH / 4; ++k) {
            float4 xv = x4[k];
            a1 = fmaf(xv.x, w1[4*k+0], a1);
            a1 = fmaf(xv.y, w1[4*k+1], a1);
            a1 = fmaf(xv.z, w1[4*k+2], a1);
            a1 = fmaf(xv.w, w1[4*k+3], a1);
            a2 = fmaf(xv.x, w2[4*k+0], a2);
            a2 = fmaf(xv.y, w2[4*k+1], a2);
            a2 = fmaf(xv.z, w2[4*k+2], a2);
            a2 = fmaf(xv.w, w2[4*k+3], a2);
            a3 = fmaf(xv.x, wr[4*k+0], a3);
            a3 = fmaf(xv.y, wr[4*k+1], a3);
            a3 = fmaf(xv.z, wr[4*k+2], a3);
            a3 = fmaf(xv.w, wr[4*k+3], a3);
        }
        lr[row + lane]   = __floats2half2_rn(a1, a2);
        hres[row + lane] = a3;
    }
    // fused degree count over real edges; returned old value = rank in segment
    for (int i = blockIdx.x * blockDim.x + threadIdx.x; i < E;
         i += gridDim.x * blockDim.x) {
        rank[i] = atomicAdd(&deg[dst[i]], 1);
    }
}

// ---------------------------------------------------------------------------
// CSR build: 3-kernel multi-block exclusive scan + atomic-free scatter.
// ---------------------------------------------------------------------------
__global__ __launch_bounds__(256) void bsum_kernel(
    const int* __restrict__ deg, int* __restrict__ bsum, int N)
{
    __shared__ int ws[4];
    int i = blockIdx.x * 256 + threadIdx.x;
    int lane = threadIdx.x & 63, wid = threadIdx.x >> 6;
    int v = (i < N) ? deg[i] : 0;
#pragma unroll
    for (int off = 32; off; off >>= 1) v += __shfl_xor(v, off);
    if (lane == 0) ws[wid] = v;
    __syncthreads();
    if (threadIdx.x == 0) bsum[blockIdx.x] = ws[0] + ws[1] + ws[2] + ws[3];
}

__global__ __launch_bounds__(64) void bscan_kernel(int* __restrict__ bsum, int nb)
{
    int lane = threadIdx.x;
    int carry = 0;
    for (int base = 0; base < nb; base += 64) {
        int i = base + lane;
        int v = (i < nb) ? bsum[i] : 0;
        int s = v;
#pragma unroll
        for (int off = 1; off < 64; off <<= 1) {
            int t = __shfl_up(s, off);
            if (lane >= off) s += t;
        }
        if (i < nb) bsum[i] = carry + s - v;   // exclusive
        carry += __shfl(s, 63);
    }
}

__global__ __launch_bounds__(256) void apply_kernel(
    const int* __restrict__ deg, const int* __restrict__ bsum,
    int* __restrict__ rowptr, int N, int total)
{
    __shared__ int ws[4];
    int i = blockIdx.x * 256 + threadIdx.x;
    int lane = threadIdx.x & 63, wid = threadIdx.x >> 6;
    int v = (i < N) ? deg[i] : 0;
    int s = v;
#pragma unroll
    for (int off = 1; off < 64; off <<= 1) {
        int t = __shfl_up(s, off);
        if (lane >= off) s += t;
    }
    if (lane == 63) ws[wid] = s;
    __syncthreads();
    int woff = 0;
    for (int w = 0; w < wid; ++w) woff += ws[w];
    int excl = bsum[blockIdx.x] + woff + s - v;
    if (i < N) rowptr[i] = excl;
    if (blockIdx.x == 0 && threadIdx.x == 0) rowptr[N] = total;
}

__global__ void scatter_kernel(const int* __restrict__ src,
                               const int* __restrict__ dst,
                               const int* __restrict__ rank,
                               const int* __restrict__ rowptr,
                               int* __restrict__ col, int E)
{
    for (int i = blockIdx.x * blockDim.x + threadIdx.x; i < E;
         i += gridDim.x * blockDim.x) {
        col[rowptr[dst[i]] + rank[i]] = src[i];
    }
}

// ---------------------------------------------------------------------------
// Pass A: per dst node (one wave, lane = channel), 3 transcendentals/edge:
//   w    = exp(sig(l_s + l_d))       (no max-pass: sigmoid bounded)
//   denL = sum w ; acc = sum r_s * w ; ft_r = acc/denL
// denR is NOT computed here (moved into passB's own loop).
// Self-loop handled analytically (own row in registers, not in CSR).
// Edge loop: batches of 8 gathers in flight, masked tail (no serial remainder).
// ---------------------------------------------------------------------------
__global__ __launch_bounds__(256) void passA_kernel(
    const __half2* __restrict__ lr,
    const int* __restrict__ rowptr, const int* __restrict__ col,
    __half2* __restrict__ rf, int N)
{
    const int node = blockIdx.x * 4 + (threadIdx.x >> 6);
    const int lane = threadIdx.x & 63;
    if (node >= N) return;
    const unsigned row = (unsigned)node * CH;
    const float2 own = __half22float2(lr[row + lane]);
    const float l_d = own.x, r_d = own.y;
    const int beg = rowptr[node], end = rowptr[node + 1];

    // self loop: arg = l_d + l_d
    float wl = __expf(1.f / (1.f + __expf(-2.f * l_d)));
    float denL = wl, acc = r_d * wl;

    int e = beg;
    while (e < end) {
        int cnt = end - e; if (cnt > 64) cnt = 64;
        int idx = e + lane; if (idx >= end) idx = end - 1;
        const int myc = col[idx];
        for (int j = 0; j < cnt; j += 8) {
            float2 f[8];
            float msk[8];
#pragma unroll
            for (int u = 0; u < 8; ++u) {
                int jj = j + u; 
                msk[u] = (jj < cnt) ? 1.f : 0.f;
                if (jj >= cnt) jj = cnt - 1;
                int s = __builtin_amdgcn_readlane(myc, jj);
                f[u] = __half22float2(lr[(unsigned)(s * CH) + lane]);
            }
#pragma unroll
            for (int u = 0; u < 8; ++u) {
                float w = __expf(1.f / (1.f + __expf(-(f[u].x + l_d))));
                w *= msk[u];
                denL += w;
                acc = fmaf(f[u].y, w, acc);
            }
        }
        e += cnt;
    }
    rf[row + lane] = __floats2half2_rn(r_d, acc / denL);  // (r, ft_r)
}

// ---------------------------------------------------------------------------
// Pass B: single loop computes BOTH numerator and softmax denominator:
//   w  = exp(sig(r_s + r_d)) ; dR = sum w ; acc = sum ftr_s * w
//   out = m0 * acc/dR + hres
// ---------------------------------------------------------------------------
__global__ __launch_bounds__(256) void passB_kernel(
    const __half2* __restrict__ rf,
    const int* __restrict__ rowptr, const int* __restrict__ col,
    const float* __restrict__ m0, float* __restrict__ out, int N)
{
    const int node = blockIdx.x * 4 + (threadIdx.x >> 6);
    const int lane = threadIdx.x & 63;
    if (node >= N) return;
    const unsigned row = (unsigned)node * CH;
    const float2 own = __half22float2(rf[row + lane]);
    const float r_d = own.x, f_own = own.y;
    const int beg = rowptr[node], end = rowptr[node + 1];

    // self loop
    float ws = __expf(1.f / (1.f + __expf(-2.f * r_d)));
    float dR = ws, acc = f_own * ws;

    int e = beg;
    while (e < end) {
        int cnt = end - e; if (cnt > 64) cnt = 64;
        int idx = e + lane; if (idx >= end) idx = end - 1;
        const int myc = col[idx];
        for (int j = 0; j < cnt; j += 8) {
            float2 f[8];
            float msk[8];
#pragma unroll
            for (int u = 0; u < 8; ++u) {
                int jj = j + u;
                msk[u] = (jj < cnt) ? 1.f : 0.f;
                if (jj >= cnt) jj = cnt - 1;
                int s = __builtin_amdgcn_readlane(myc, jj);
                f[u] = __half22float2(rf[(unsigned)(s * CH) + lane]);
            }
#pragma unroll
            for (int u = 0; u < 8; ++u) {
                float w = __expf(1.f / (1.f + __expf(-(f[u].x + r_d))));
                w *= msk[u];
                dR += w;
                acc = fmaf(f[u].y, w, acc);
            }
        }
        e += cnt;
    }
    out[row + lane] = fmaf(m0[lane], acc / dR, out[row + lane]);
}

// ---------------------------------------------------------------------------
extern "C" void kernel_launch(void* const* d_in, const int* in_sizes, int n_in,
                              void* d_out, int out_size, void* d_ws, size_t ws_size,
                              hipStream_t stream)
{
    const float* ndata = (const float*)d_in[0];
    const int*   src   = (const int*)d_in[1];
    const int*   dst   = (const int*)d_in[2];
    const float* W1    = (const float*)d_in[3];
    const float* b1    = (const float*)d_in[4];
    const float* W2    = (const float*)d_in[5];
    const float* b2    = (const float*)d_in[6];
    const float* Wr    = (const float*)d_in[7];
    const float* br    = (const float*)d_in[8];
    const float* m     = (const float*)d_in[9];   // [3,8,8]; m[0] flat = 64
    float* out = (float*)d_out;

    const int N = in_sizes[0] / CH;
    const int E = in_sizes[1];
    const int nbk = (N + 255) / 256;

    char* ws = (char*)d_ws;
    size_t off = 0;
    auto alloc = [&](size_t bytes) -> void* {
        void* p = ws + off;
        off = (off + bytes + 255) & ~(size_t)255;
        return p;
    };
    __half2* lr   = (__half2*)alloc((size_t)N * CH * 4);
    __half2* rf   = (__half2*)alloc((size_t)N * CH * 4);
    int*   deg    = (int*)alloc((size_t)N * 4);
    int*   bsum   = (int*)alloc((size_t)nbk * 4);
    int*   rowptr = (int*)alloc((size_t)(N + 1) * 4);
    int*   rank   = (int*)alloc((size_t)E * 4);
    int*   col    = (int*)alloc((size_t)E * 4);

    hipMemsetAsync(deg, 0, (size_t)N * 4, stream);
    proj_kernel<<<512, 256, 0, stream>>>(ndata, W1, b1, W2, b2, Wr, br,
                                         lr, out, dst, deg, rank, N, E);
    bsum_kernel<<<nbk, 256, 0, stream>>>(deg, bsum, N);
    bscan_kernel<<<1, 64, 0, stream>>>(bsum, nbk);
    apply_kernel<<<nbk, 256, 0, stream>>>(deg, bsum, rowptr, N, E);
    scatter_kernel<<<1024, 256, 0, stream>>>(src, dst, rank, rowptr, col, E);
    int nb = (N + 3) / 4;
    passA_kernel<<<nb, 256, 0, stream>>>(lr, rowptr, col, rf, N);
    passB_kernel<<<nb, 256, 0, stream>>>(rf, rowptr, col, m, out, N);
}

// Round 6
// 281.320 us; speedup vs baseline: 1.6120x; 1.0141x over previous
//
#include <hip/hip_runtime.h>
#include <hip/hip_fp16.h>

#define CH 64

// ---------------------------------------------------------------------------
// count: per-edge degree histogram; the atomicAdd return value is the edge's
// rank within its dst segment (makes the later scatter atomic-free).
// Separate kernel (not fused in proj) so the random-address atomic latency
// is hidden by high wave count.
// ---------------------------------------------------------------------------
__global__ void count_kernel(const int* __restrict__ dst, int* __restrict__ deg,
                             int* __restrict__ rank, int E)
{
    for (int i = blockIdx.x * blockDim.x + threadIdx.x; i < E;
         i += gridDim.x * blockDim.x) {
        rank[i] = atomicAdd(&deg[dst[i]], 1);
    }
}

// ---------------------------------------------------------------------------
// proj: per-node minmax norm + three 64x64 GEMVs -> lr[node][ch]=half2(l,r),
// residual into d_out. One wave per node; lane = output channel; W-columns
// in VGPRs; x-row broadcast via per-wave LDS buffer.
// grid=1024 blocks: 4 blocks/CU -> 4 waves/SIMD (VGPR=128 cap).
// ---------------------------------------------------------------------------
__global__ __launch_bounds__(256) void proj_kernel(
    const float* __restrict__ nd,
    const float* __restrict__ W1, const float* __restrict__ b1,
    const float* __restrict__ W2, const float* __restrict__ b2,
    const float* __restrict__ Wr, const float* __restrict__ br,
    __half2* __restrict__ lr, float* __restrict__ hres, int N)
{
    __shared__ __align__(16) float xs[4][CH];
    const int lane = threadIdx.x & 63;
    const int wid  = threadIdx.x >> 6;

    float w1[CH], w2[CH], wr[CH];
#pragma unroll
    for (int i = 0; i < CH; ++i) {
        w1[i] = W1[i * CH + lane];
        w2[i] = W2[i * CH + lane];
        wr[i] = Wr[i * CH + lane];
    }
    const float bb1 = b1[lane], bb2 = b2[lane], bbr = br[lane];

    const int nwave = gridDim.x * 4;
    for (int node = blockIdx.x * 4 + wid; node < N; node += nwave) {
        const unsigned row = (unsigned)node * CH;
        float v = nd[row + lane];
        float mn = v, mx = v;
#pragma unroll
        for (int off = 32; off; off >>= 1) {
            mn = fminf(mn, __shfl_xor(mn, off));
            mx = fmaxf(mx, __shfl_xor(mx, off));
        }
        float x = (v - mn) / (mx - mn + 1e-5f);
        xs[wid][lane] = x;
        float a1 = bb1, a2 = bb2, a3 = bbr;
        const float4* x4 = reinterpret_cast<const float4*>(&xs[wid][0]);
#pragma unroll
        for (int k = 0; k < CH / 4; ++k) {
            float4 xv = x4[k];
            a1 = fmaf(xv.x, w1[4*k+0], a1);
            a1 = fmaf(xv.y, w1[4*k+1], a1);
            a1 = fmaf(xv.z, w1[4*k+2], a1);
            a1 = fmaf(xv.w, w1[4*k+3], a1);
            a2 = fmaf(xv.x, w2[4*k+0], a2);
            a2 = fmaf(xv.y, w2[4*k+1], a2);
            a2 = fmaf(xv.z, w2[4*k+2], a2);
            a2 = fmaf(xv.w, w2[4*k+3], a2);
            a3 = fmaf(xv.x, wr[4*k+0], a3);
            a3 = fmaf(xv.y, wr[4*k+1], a3);
            a3 = fmaf(xv.z, wr[4*k+2], a3);
            a3 = fmaf(xv.w, wr[4*k+3], a3);
        }
        lr[row + lane]   = __floats2half2_rn(a1, a2);
        hres[row + lane] = a3;
    }
}

// ---------------------------------------------------------------------------
// CSR build: 3-kernel multi-block exclusive scan + atomic-free scatter.
// ---------------------------------------------------------------------------
__global__ __launch_bounds__(256) void bsum_kernel(
    const int* __restrict__ deg, int* __restrict__ bsum, int N)
{
    __shared__ int ws[4];
    int i = blockIdx.x * 256 + threadIdx.x;
    int lane = threadIdx.x & 63, wid = threadIdx.x >> 6;
    int v = (i < N) ? deg[i] : 0;
#pragma unroll
    for (int off = 32; off; off >>= 1) v += __shfl_xor(v, off);
    if (lane == 0) ws[wid] = v;
    __syncthreads();
    if (threadIdx.x == 0) bsum[blockIdx.x] = ws[0] + ws[1] + ws[2] + ws[3];
}

__global__ __launch_bounds__(64) void bscan_kernel(int* __restrict__ bsum, int nb)
{
    int lane = threadIdx.x;
    int carry = 0;
    for (int base = 0; base < nb; base += 64) {
        int i = base + lane;
        int v = (i < nb) ? bsum[i] : 0;
        int s = v;
#pragma unroll
        for (int off = 1; off < 64; off <<= 1) {
            int t = __shfl_up(s, off);
            if (lane >= off) s += t;
        }
        if (i < nb) bsum[i] = carry + s - v;   // exclusive
        carry += __shfl(s, 63);
    }
}

__global__ __launch_bounds__(256) void apply_kernel(
    const int* __restrict__ deg, const int* __restrict__ bsum,
    int* __restrict__ rowptr, int N, int total)
{
    __shared__ int ws[4];
    int i = blockIdx.x * 256 + threadIdx.x;
    int lane = threadIdx.x & 63, wid = threadIdx.x >> 6;
    int v = (i < N) ? deg[i] : 0;
    int s = v;
#pragma unroll
    for (int off = 1; off < 64; off <<= 1) {
        int t = __shfl_up(s, off);
        if (lane >= off) s += t;
    }
    if (lane == 63) ws[wid] = s;
    __syncthreads();
    int woff = 0;
    for (int w = 0; w < wid; ++w) woff += ws[w];
    int excl = bsum[blockIdx.x] + woff + s - v;
    if (i < N) rowptr[i] = excl;
    if (blockIdx.x == 0 && threadIdx.x == 0) rowptr[N] = total;
}

__global__ void scatter_kernel(const int* __restrict__ src,
                               const int* __restrict__ dst,
                               const int* __restrict__ rank,
                               const int* __restrict__ rowptr,
                               int* __restrict__ col, int E)
{
    for (int i = blockIdx.x * blockDim.x + threadIdx.x; i < E;
         i += gridDim.x * blockDim.x) {
        col[rowptr[dst[i]] + rank[i]] = src[i];
    }
}

// ---------------------------------------------------------------------------
// Pass A: per dst node (one wave, lane = channel), 3 transcendentals/edge:
//   w = exp(sig(l_s + l_d)) ; denL = sum w ; acc = sum r_s*w ; ft_r = acc/denL
// denR moved into passB. Self-loop analytic (own row in registers).
// Edge loop: batches of 8 gathers in flight, masked tail.
// ---------------------------------------------------------------------------
__global__ __launch_bounds__(256) void passA_kernel(
    const __half2* __restrict__ lr,
    const int* __restrict__ rowptr, const int* __restrict__ col,
    __half2* __restrict__ rf, int N)
{
    const int node = blockIdx.x * 4 + (threadIdx.x >> 6);
    const int lane = threadIdx.x & 63;
    if (node >= N) return;
    const unsigned row = (unsigned)node * CH;
    const float2 own = __half22float2(lr[row + lane]);
    const float l_d = own.x, r_d = own.y;
    const int beg = rowptr[node], end = rowptr[node + 1];

    float wl = __expf(1.f / (1.f + __expf(-2.f * l_d)));
    float denL = wl, acc = r_d * wl;

    int e = beg;
    while (e < end) {
        int cnt = end - e; if (cnt > 64) cnt = 64;
        int idx = e + lane; if (idx >= end) idx = end - 1;
        const int myc = col[idx];
        for (int j = 0; j < cnt; j += 8) {
            float2 f[8];
            float msk[8];
#pragma unroll
            for (int u = 0; u < 8; ++u) {
                int jj = j + u;
                msk[u] = (jj < cnt) ? 1.f : 0.f;
                if (jj >= cnt) jj = cnt - 1;
                int s = __builtin_amdgcn_readlane(myc, jj);
                f[u] = __half22float2(lr[(unsigned)(s * CH) + lane]);
            }
#pragma unroll
            for (int u = 0; u < 8; ++u) {
                float w = __expf(1.f / (1.f + __expf(-(f[u].x + l_d))));
                w *= msk[u];
                denL += w;
                acc = fmaf(f[u].y, w, acc);
            }
        }
        e += cnt;
    }
    rf[row + lane] = __floats2half2_rn(r_d, acc / denL);  // (r, ft_r)
}

// ---------------------------------------------------------------------------
// Pass B: single loop computes numerator AND softmax denominator:
//   w = exp(sig(r_s + r_d)) ; dR = sum w ; acc = sum ftr_s*w
//   out = m0 * acc/dR + hres
// ---------------------------------------------------------------------------
__global__ __launch_bounds__(256) void passB_kernel(
    const __half2* __restrict__ rf,
    const int* __restrict__ rowptr, const int* __restrict__ col,
    const float* __restrict__ m0, float* __restrict__ out, int N)
{
    const int node = blockIdx.x * 4 + (threadIdx.x >> 6);
    const int lane = threadIdx.x & 63;
    if (node >= N) return;
    const unsigned row = (unsigned)node * CH;
    const float2 own = __half22float2(rf[row + lane]);
    const float r_d = own.x, f_own = own.y;
    const int beg = rowptr[node], end = rowptr[node + 1];

    float ws = __expf(1.f / (1.f + __expf(-2.f * r_d)));
    float dR = ws, acc = f_own * ws;

    int e = beg;
    while (e < end) {
        int cnt = end - e; if (cnt > 64) cnt = 64;
        int idx = e + lane; if (idx >= end) idx = end - 1;
        const int myc = col[idx];
        for (int j = 0; j < cnt; j += 8) {
            float2 f[8];
            float msk[8];
#pragma unroll
            for (int u = 0; u < 8; ++u) {
                int jj = j + u;
                msk[u] = (jj < cnt) ? 1.f : 0.f;
                if (jj >= cnt) jj = cnt - 1;
                int s = __builtin_amdgcn_readlane(myc, jj);
                f[u] = __half22float2(rf[(unsigned)(s * CH) + lane]);
            }
#pragma unroll
            for (int u = 0; u < 8; ++u) {
                float w = __expf(1.f / (1.f + __expf(-(f[u].x + r_d))));
                w *= msk[u];
                dR += w;
                acc = fmaf(f[u].y, w, acc);
            }
        }
        e += cnt;
    }
    out[row + lane] = fmaf(m0[lane], acc / dR, out[row + lane]);
}

// ---------------------------------------------------------------------------
extern "C" void kernel_launch(void* const* d_in, const int* in_sizes, int n_in,
                              void* d_out, int out_size, void* d_ws, size_t ws_size,
                              hipStream_t stream)
{
    const float* ndata = (const float*)d_in[0];
    const int*   src   = (const int*)d_in[1];
    const int*   dst   = (const int*)d_in[2];
    const float* W1    = (const float*)d_in[3];
    const float* b1    = (const float*)d_in[4];
    const float* W2    = (const float*)d_in[5];
    const float* b2    = (const float*)d_in[6];
    const float* Wr    = (const float*)d_in[7];
    const float* br    = (const float*)d_in[8];
    const float* m     = (const float*)d_in[9];   // [3,8,8]; m[0] flat = 64
    float* out = (float*)d_out;

    const int N = in_sizes[0] / CH;
    const int E = in_sizes[1];
    const int nbk = (N + 255) / 256;

    char* ws = (char*)d_ws;
    size_t off = 0;
    auto alloc = [&](size_t bytes) -> void* {
        void* p = ws + off;
        off = (off + bytes + 255) & ~(size_t)255;
        return p;
    };
    __half2* lr   = (__half2*)alloc((size_t)N * CH * 4);
    __half2* rf   = (__half2*)alloc((size_t)N * CH * 4);
    int*   deg    = (int*)alloc((size_t)N * 4);
    int*   bsum   = (int*)alloc((size_t)nbk * 4);
    int*   rowptr = (int*)alloc((size_t)(N + 1) * 4);
    int*   rank   = (int*)alloc((size_t)E * 4);
    int*   col    = (int*)alloc((size_t)E * 4);

    hipMemsetAsync(deg, 0, (size_t)N * 4, stream);
    count_kernel<<<2048, 256, 0, stream>>>(dst, deg, rank, E);
    proj_kernel<<<1024, 256, 0, stream>>>(ndata, W1, b1, W2, b2, Wr, br,
                                          lr, out, N);
    bsum_kernel<<<nbk, 256, 0, stream>>>(deg, bsum, N);
    bscan_kernel<<<1, 64, 0, stream>>>(bsum, nbk);
    apply_kernel<<<nbk, 256, 0, stream>>>(deg, bsum, rowptr, N, E);
    scatter_kernel<<<2048, 256, 0, stream>>>(src, dst, rank, rowptr, col, E);
    int nb = (N + 3) / 4;
    passA_kernel<<<nb, 256, 0, stream>>>(lr, rowptr, col, rf, N);
    passB_kernel<<<nb, 256, 0, stream>>>(rf, rowptr, col, m, out, N);
}

// Round 7
// 236.469 us; speedup vs baseline: 1.9178x; 1.1897x over previous
//
#include <hip/hip_runtime.h>
#include <hip/hip_fp16.h>

#define CH 64
#define LOG2E  1.44269504f
#define MLOG2E -1.44269504f

// v_exp_f32 computes 2^x (ISA §3). Pure op, no volatile -> schedulable/CSE-able.
__device__ __forceinline__ float exp2fast(float x) {
    float r; asm("v_exp_f32 %0, %1" : "=v"(r) : "v"(x)); return r;
}

// ---------------------------------------------------------------------------
// count: degree histogram; atomicAdd return value = edge's rank in its dst
// segment (makes scatter atomic-free).
// ---------------------------------------------------------------------------
__global__ void count_kernel(const int* __restrict__ dst, int* __restrict__ deg,
                             int* __restrict__ rank, int E)
{
    for (int i = blockIdx.x * blockDim.x + threadIdx.x; i < E;
         i += gridDim.x * blockDim.x) {
        rank[i] = atomicAdd(&deg[dst[i]], 1);
    }
}

// ---------------------------------------------------------------------------
// proj: per-node minmax norm + three 64x64 GEMVs -> lr=half2(l,r), residual
// into d_out. One wave/node, lane = out channel, W-columns in VGPRs.
// ---------------------------------------------------------------------------
__global__ __launch_bounds__(256) void proj_kernel(
    const float* __restrict__ nd,
    const float* __restrict__ W1, const float* __restrict__ b1,
    const float* __restrict__ W2, const float* __restrict__ b2,
    const float* __restrict__ Wr, const float* __restrict__ br,
    __half2* __restrict__ lr, float* __restrict__ hres, int N)
{
    __shared__ __align__(16) float xs[4][CH];
    const int lane = threadIdx.x & 63;
    const int wid  = threadIdx.x >> 6;

    float w1[CH], w2[CH], wr[CH];
#pragma unroll
    for (int i = 0; i < CH; ++i) {
        w1[i] = W1[i * CH + lane];
        w2[i] = W2[i * CH + lane];
        wr[i] = Wr[i * CH + lane];
    }
    const float bb1 = b1[lane], bb2 = b2[lane], bbr = br[lane];

    const int nwave = gridDim.x * 4;
    for (int node = blockIdx.x * 4 + wid; node < N; node += nwave) {
        const unsigned row = (unsigned)node * CH;
        float v = nd[row + lane];
        float mn = v, mx = v;
#pragma unroll
        for (int off = 32; off; off >>= 1) {
            mn = fminf(mn, __shfl_xor(mn, off));
            mx = fmaxf(mx, __shfl_xor(mx, off));
        }
        float x = (v - mn) / (mx - mn + 1e-5f);
        xs[wid][lane] = x;
        float a1 = bb1, a2 = bb2, a3 = bbr;
        const float4* x4 = reinterpret_cast<const float4*>(&xs[wid][0]);
#pragma unroll
        for (int k = 0; k < CH / 4; ++k) {
            float4 xv = x4[k];
            a1 = fmaf(xv.x, w1[4*k+0], a1);
            a1 = fmaf(xv.y, w1[4*k+1], a1);
            a1 = fmaf(xv.z, w1[4*k+2], a1);
            a1 = fmaf(xv.w, w1[4*k+3], a1);
            a2 = fmaf(xv.x, w2[4*k+0], a2);
            a2 = fmaf(xv.y, w2[4*k+1], a2);
            a2 = fmaf(xv.z, w2[4*k+2], a2);
            a2 = fmaf(xv.w, w2[4*k+3], a2);
            a3 = fmaf(xv.x, wr[4*k+0], a3);
            a3 = fmaf(xv.y, wr[4*k+1], a3);
            a3 = fmaf(xv.z, wr[4*k+2], a3);
            a3 = fmaf(xv.w, wr[4*k+3], a3);
        }
        lr[row + lane]   = __floats2half2_rn(a1, a2);
        hres[row + lane] = a3;
    }
}

// ---------------------------------------------------------------------------
// CSR build: 3-kernel multi-block exclusive scan + atomic-free scatter.
// ---------------------------------------------------------------------------
__global__ __launch_bounds__(256) void bsum_kernel(
    const int* __restrict__ deg, int* __restrict__ bsum, int N)
{
    __shared__ int ws[4];
    int i = blockIdx.x * 256 + threadIdx.x;
    int lane = threadIdx.x & 63, wid = threadIdx.x >> 6;
    int v = (i < N) ? deg[i] : 0;
#pragma unroll
    for (int off = 32; off; off >>= 1) v += __shfl_xor(v, off);
    if (lane == 0) ws[wid] = v;
    __syncthreads();
    if (threadIdx.x == 0) bsum[blockIdx.x] = ws[0] + ws[1] + ws[2] + ws[3];
}

__global__ __launch_bounds__(64) void bscan_kernel(int* __restrict__ bsum, int nb)
{
    int lane = threadIdx.x;
    int carry = 0;
    for (int base = 0; base < nb; base += 64) {
        int i = base + lane;
        int v = (i < nb) ? bsum[i] : 0;
        int s = v;
#pragma unroll
        for (int off = 1; off < 64; off <<= 1) {
            int t = __shfl_up(s, off);
            if (lane >= off) s += t;
        }
        if (i < nb) bsum[i] = carry + s - v;   // exclusive
        carry += __shfl(s, 63);
    }
}

__global__ __launch_bounds__(256) void apply_kernel(
    const int* __restrict__ deg, const int* __restrict__ bsum,
    int* __restrict__ rowptr, int N, int total)
{
    __shared__ int ws[4];
    int i = blockIdx.x * 256 + threadIdx.x;
    int lane = threadIdx.x & 63, wid = threadIdx.x >> 6;
    int v = (i < N) ? deg[i] : 0;
    int s = v;
#pragma unroll
    for (int off = 1; off < 64; off <<= 1) {
        int t = __shfl_up(s, off);
        if (lane >= off) s += t;
    }
    if (lane == 63) ws[wid] = s;
    __syncthreads();
    int woff = 0;
    for (int w = 0; w < wid; ++w) woff += ws[w];
    int excl = bsum[blockIdx.x] + woff + s - v;
    if (i < N) rowptr[i] = excl;
    if (blockIdx.x == 0 && threadIdx.x == 0) rowptr[N] = total;
}

__global__ void scatter_kernel(const int* __restrict__ src,
                               const int* __restrict__ dst,
                               const int* __restrict__ rank,
                               const int* __restrict__ rowptr,
                               int* __restrict__ col, int E)
{
    for (int i = blockIdx.x * blockDim.x + threadIdx.x; i < E;
         i += gridDim.x * blockDim.x) {
        col[rowptr[dst[i]] + rank[i]] = src[i];
    }
}

// ---------------------------------------------------------------------------
// Edge batch macros: gather U half2 rows (ILP=U), then the exp2-form weight:
//   u = 2^(fma(x, -log2e, nl_d))  ; s = rcp(1+u) ; w = 2^(log2e * s)
// Exact tails 16/8/4/2/1 (wave-uniform branches) -> zero padded work.
// ---------------------------------------------------------------------------
#define EDGE_BATCH(U_, TBL_, STEP_)                                          \
    {                                                                        \
        __half2 hb[U_];                                                      \
        _Pragma("unroll")                                                    \
        for (int u = 0; u < (U_); ++u) {                                     \
            int s_ = __builtin_amdgcn_readlane(myc, j + u);                  \
            hb[u] = TBL_[(unsigned)(s_ * CH) + lane];                        \
        }                                                                    \
        _Pragma("unroll")                                                    \
        for (int u = 0; u < (U_); ++u) { STEP_(hb[u]); }                     \
        j += (U_);                                                           \
    }

// ---------------------------------------------------------------------------
// Pass A: per dst node (one wave, lane = channel):
//   w = exp(sig(l_s+l_d)) ; denL = sum w ; acc = sum r_s*w ; ft_r = acc/denL
// Self-loop analytic. denR deferred to passB.
// ---------------------------------------------------------------------------
__global__ __launch_bounds__(256) void passA_kernel(
    const __half2* __restrict__ lr,
    const int* __restrict__ rowptr, const int* __restrict__ col,
    __half2* __restrict__ rf, int N)
{
    const int node = blockIdx.x * 4 + (threadIdx.x >> 6);
    const int lane = threadIdx.x & 63;
    if (node >= N) return;
    const unsigned row = (unsigned)node * CH;
    const float2 own = __half22float2(lr[row + lane]);
    const float l_d = own.x, r_d = own.y;
    const float nl_d = MLOG2E * l_d;
    const int beg = rowptr[node], end = rowptr[node + 1];

    // self loop: t = 2*l_d
    float wl = exp2fast(LOG2E * __builtin_amdgcn_rcpf(1.f + exp2fast(2.f * nl_d)));
    float denL = wl, acc = r_d * wl;

#define A_STEP(H_) {                                                         \
        float2 f = __half22float2(H_);                                       \
        float uu = exp2fast(fmaf(f.x, MLOG2E, nl_d));                        \
        float w  = exp2fast(LOG2E * __builtin_amdgcn_rcpf(1.f + uu));        \
        denL += w; acc = fmaf(f.y, w, acc); }

    int e = beg;
    while (e < end) {
        int cnt = end - e; if (cnt > 64) cnt = 64;
        int idx = e + lane; if (idx >= end) idx = end - 1;
        const int myc = col[idx];
        int j = 0;
        int nfull = cnt >> 4;
        for (int b = 0; b < nfull; ++b) EDGE_BATCH(16, lr, A_STEP)
        if (cnt & 8) EDGE_BATCH(8, lr, A_STEP)
        if (cnt & 4) EDGE_BATCH(4, lr, A_STEP)
        if (cnt & 2) EDGE_BATCH(2, lr, A_STEP)
        if (cnt & 1) EDGE_BATCH(1, lr, A_STEP)
        e += cnt;
    }
    rf[row + lane] = __floats2half2_rn(r_d, acc / denL);  // (r, ft_r)
}

// ---------------------------------------------------------------------------
// Pass B: numerator AND softmax denominator in one loop:
//   w = exp(sig(r_s+r_d)) ; dR = sum w ; acc = sum ftr_s*w
//   out = m0 * acc/dR + hres
// ---------------------------------------------------------------------------
__global__ __launch_bounds__(256) void passB_kernel(
    const __half2* __restrict__ rf,
    const int* __restrict__ rowptr, const int* __restrict__ col,
    const float* __restrict__ m0, float* __restrict__ out, int N)
{
    const int node = blockIdx.x * 4 + (threadIdx.x >> 6);
    const int lane = threadIdx.x & 63;
    if (node >= N) return;
    const unsigned row = (unsigned)node * CH;
    const float2 own = __half22float2(rf[row + lane]);
    const float r_d = own.x, f_own = own.y;
    const float nr_d = MLOG2E * r_d;
    const int beg = rowptr[node], end = rowptr[node + 1];

    float wsl = exp2fast(LOG2E * __builtin_amdgcn_rcpf(1.f + exp2fast(2.f * nr_d)));
    float dR = wsl, acc = f_own * wsl;

#define B_STEP(H_) {                                                         \
        float2 f = __half22float2(H_);                                       \
        float uu = exp2fast(fmaf(f.x, MLOG2E, nr_d));                        \
        float w  = exp2fast(LOG2E * __builtin_amdgcn_rcpf(1.f + uu));        \
        dR += w; acc = fmaf(f.y, w, acc); }

    int e = beg;
    while (e < end) {
        int cnt = end - e; if (cnt > 64) cnt = 64;
        int idx = e + lane; if (idx >= end) idx = end - 1;
        const int myc = col[idx];
        int j = 0;
        int nfull = cnt >> 4;
        for (int b = 0; b < nfull; ++b) EDGE_BATCH(16, rf, B_STEP)
        if (cnt & 8) EDGE_BATCH(8, rf, B_STEP)
        if (cnt & 4) EDGE_BATCH(4, rf, B_STEP)
        if (cnt & 2) EDGE_BATCH(2, rf, B_STEP)
        if (cnt & 1) EDGE_BATCH(1, rf, B_STEP)
        e += cnt;
    }
    out[row + lane] = fmaf(m0[lane], acc / dR, out[row + lane]);
}

// ---------------------------------------------------------------------------
extern "C" void kernel_launch(void* const* d_in, const int* in_sizes, int n_in,
                              void* d_out, int out_size, void* d_ws, size_t ws_size,
                              hipStream_t stream)
{
    const float* ndata = (const float*)d_in[0];
    const int*   src   = (const int*)d_in[1];
    const int*   dst   = (const int*)d_in[2];
    const float* W1    = (const float*)d_in[3];
    const float* b1    = (const float*)d_in[4];
    const float* W2    = (const float*)d_in[5];
    const float* b2    = (const float*)d_in[6];
    const float* Wr    = (const float*)d_in[7];
    const float* br    = (const float*)d_in[8];
    const float* m     = (const float*)d_in[9];   // [3,8,8]; m[0] flat = 64
    float* out = (float*)d_out;

    const int N = in_sizes[0] / CH;
    const int E = in_sizes[1];
    const int nbk = (N + 255) / 256;

    char* ws = (char*)d_ws;
    size_t off = 0;
    auto alloc = [&](size_t bytes) -> void* {
        void* p = ws + off;
        off = (off + bytes + 255) & ~(size_t)255;
        return p;
    };
    __half2* lr   = (__half2*)alloc((size_t)N * CH * 4);
    __half2* rf   = (__half2*)alloc((size_t)N * CH * 4);
    int*   deg    = (int*)alloc((size_t)N * 4);
    int*   bsum   = (int*)alloc((size_t)nbk * 4);
    int*   rowptr = (int*)alloc((size_t)(N + 1) * 4);
    int*   rank   = (int*)alloc((size_t)E * 4);
    int*   col    = (int*)alloc((size_t)E * 4);

    hipMemsetAsync(deg, 0, (size_t)N * 4, stream);
    count_kernel<<<2048, 256, 0, stream>>>(dst, deg, rank, E);
    proj_kernel<<<1024, 256, 0, stream>>>(ndata, W1, b1, W2, b2, Wr, br,
                                          lr, out, N);
    bsum_kernel<<<nbk, 256, 0, stream>>>(deg, bsum, N);
    bscan_kernel<<<1, 64, 0, stream>>>(bsum, nbk);
    apply_kernel<<<nbk, 256, 0, stream>>>(deg, bsum, rowptr, N, E);
    scatter_kernel<<<2048, 256, 0, stream>>>(src, dst, rank, rowptr, col, E);
    int nb = (N + 3) / 4;
    passA_kernel<<<nb, 256, 0, stream>>>(lr, rowptr, col, rf, N);
    passB_kernel<<<nb, 256, 0, stream>>>(rf, rowptr, col, m, out, N);
}